// Round 6
// baseline (1920.397 us; speedup 1.0000x reference)
//
#include <hip/hip_runtime.h>
#include <hip/hip_bf16.h>
#include <stdint.h>

// BinaryTreeLSTM on MI355X (gfx950) — round 6.
// Persistent single kernel (no launch gaps), per-level GEMM+cell fused.
// Key fixes vs R3-R5 (which were VMEM-segment-bound / spill-bound):
//  - A staged into LDS with COALESCED accesses only: 8-row x 128B pieces,
//    global_load_lds (h, bf16) or reg-convert + ds_write_b128 (x, fp32).
//  - B-frags loaded straight from frag-packed PW with coalesced 16B/lane
//    loads into registers (no B LDS, no B restage traffic).
//  - LDS = A double-buffer 2x32KB = 64KB -> exactly 2 blocks/CU (grid 512
//    co-resident, 8 waves/CU for latency overlap).
//  - XOR-swizzled A slots (slot = idx8 ^ (row&7)): frag ds_read_b128 is
//    4-way-conflicted (1.58x) instead of 32-way.
//  - Grid barrier counter in __device__ global with persisted epoch base.

#define BATCH 256
#define TDEPTH 10
#define NTOT 1023
#define HDIM 128
#define NCLS 5
#define GDIM 384
#define NBLK 512
#define NBAR 11

typedef __bf16 bf16x8 __attribute__((ext_vector_type(8)));
typedef float f32x16 __attribute__((ext_vector_type(16)));

__device__ unsigned g_ctr;    // zero-init at load; monotonic across launches
__device__ unsigned g_base;   // epoch base, updated at end of each launch

__device__ __forceinline__ float sigmoid_f(float v) { return 1.f / (1.f + __expf(-v)); }
__device__ __forceinline__ float tanh_f(float v) { return 1.f - 2.f / (1.f + __expf(2.f * v)); }

__device__ __forceinline__ void load_lds16(const void* g, void* l) {
  __builtin_amdgcn_global_load_lds((const __attribute__((address_space(1))) unsigned int*)g,
                                   (__attribute__((address_space(3))) unsigned int*)l, 16, 0, 0);
}

__device__ __forceinline__ void gbar(unsigned base, unsigned k) {
  __syncthreads();
  if (threadIdx.x == 0) {
    __threadfence();
    __hip_atomic_fetch_add(&g_ctr, 1u, __ATOMIC_RELAXED, __HIP_MEMORY_SCOPE_AGENT);
    while ((unsigned)(__hip_atomic_load(&g_ctr, __ATOMIC_RELAXED, __HIP_MEMORY_SCOPE_AGENT) - base)
           < k * (unsigned)NBLK)
      __builtin_amdgcn_s_sleep(1);
    (void)__hip_atomic_load(&g_ctr, __ATOMIC_ACQUIRE, __HIP_MEMORY_SCOPE_AGENT);
  }
  __syncthreads();
}

template<bool LEAF>
__device__ __forceinline__ void level_body(
    unsigned char* Ab,
    const float* __restrict__ x, const __bf16* __restrict__ PW,
    const __bf16* __restrict__ h_prev, const float* __restrict__ c_prev,
    __bf16* __restrict__ h_out, float* __restrict__ c_out,
    int d, int jt, int stripe,
    float b0, float b1, float b2, float b3, float b4, int j)
{
  const int tid = threadIdx.x;
  const int w = tid >> 6;
  const int l = tid & 63;
  const int l31 = l & 31;
  const int hh = l >> 5;
  const int idx8 = (l & 7) ^ (l >> 3);   // swizzled k-slot this lane stages
  const int n = 1 << d;
  const int tiles = 1 << d;
  const int rh = hh * 4;
  constexpr int NCH = LEAF ? 2 : 6;      // K-chunks of 64

  for (int t = stripe; t < tiles; t += 128) {
    // per-piece source row pointers (wave w stages rows [64w, 64w+64))
    const float* xs[8];
    const __bf16* hs[8];
#pragma unroll
    for (int pi = 0; pi < 8; ++pi) {
      int r = 64 * w + 8 * pi + (l >> 3);
      int m = t * 256 + r;
      int b = m >> d;
      int id = m & (n - 1);
      xs[pi] = x + ((size_t)(b * NTOT + (n - 1) + id)) * HDIM;
      if (!LEAF) hs[pi] = h_prev + ((size_t)b * 2 * n + 2 * id) * HDIM;
      else hs[pi] = nullptr;
    }

    auto stage = [&](int kt) {
      unsigned char* Ax = Ab + (kt & 1) * 32768;
      if (LEAF || kt < 2) {
        const int koff = kt * 64 + idx8 * 8;   // floats within x row
#pragma unroll
        for (int pi = 0; pi < 8; ++pi) {
          const float* s = xs[pi] + koff;
          float4 v0 = *(const float4*)s;
          float4 v1 = *(const float4*)(s + 4);
          bf16x8 wv;
          wv[0] = (__bf16)v0.x; wv[1] = (__bf16)v0.y; wv[2] = (__bf16)v0.z; wv[3] = (__bf16)v0.w;
          wv[4] = (__bf16)v1.x; wv[5] = (__bf16)v1.y; wv[6] = (__bf16)v1.z; wv[7] = (__bf16)v1.w;
          *(bf16x8*)(Ax + (64 * w + 8 * pi) * 128 + l * 16) = wv;
        }
      } else {
        // kt 2,3: left child halves; kt 4,5: right child halves (bf16)
        const int koff = (kt & 1) * 64 + ((kt >= 4) ? 128 : 0) + idx8 * 8;
#pragma unroll
        for (int pi = 0; pi < 8; ++pi)
          load_lds16(hs[pi] + koff, Ax + (64 * w + 8 * pi) * 128);
      }
    };

    f32x16 acc[2][5];
#pragma unroll
    for (int f = 0; f < 2; ++f)
#pragma unroll
      for (int g = 0; g < 5; ++g)
#pragma unroll
        for (int r = 0; r < 16; ++r) acc[f][g][r] = 0.f;

    stage(0);
    for (int kt = 0; kt < NCH; ++kt) {
      __syncthreads();                    // chunk kt staged; buf (kt+1)&1 free
      if (kt + 1 < NCH) stage(kt + 1);
      // B fragments: coalesced 16B/lane from frag-packed PW (L2-resident)
      bf16x8 breg[4][5];
#pragma unroll
      for (int kk = 0; kk < 4; ++kk)
#pragma unroll
        for (int g = 0; g < 5; ++g) {
          if (LEAF && (g == 1 || g == 2)) continue;
          breg[kk][g] = *(const bf16x8*)(PW +
              (((size_t)(g * 4 + jt) * 24 + kt * 4 + kk) * 64 + l) * 8);
        }
      const unsigned char* Ax = Ab + (kt & 1) * 32768;
#pragma unroll
      for (int kk = 0; kk < 4; ++kk) {
        const int sw = ((kk * 2 + hh) ^ (l & 7)) * 16;
        bf16x8 a0 = *(const bf16x8*)(Ax + (w * 32 + l31) * 128 + sw);
        bf16x8 a1 = *(const bf16x8*)(Ax + (128 + w * 32 + l31) * 128 + sw);
#pragma unroll
        for (int g = 0; g < 5; ++g) {
          if (LEAF && (g == 1 || g == 2)) continue;
          acc[0][g] = __builtin_amdgcn_mfma_f32_32x32x16_bf16(a0, breg[kk][g], acc[0][g], 0, 0, 0);
          acc[1][g] = __builtin_amdgcn_mfma_f32_32x32x16_bf16(a1, breg[kk][g], acc[1][g], 0, 0, 0);
        }
      }
    }

    // epilogue: D layout col(j)=lane&31, row=(r&3)+8*(r>>2)+4*(lane>>5)
#pragma unroll
    for (int f = 0; f < 2; ++f) {
      const int mb = t * 256 + f * 128 + w * 32 + rh;
#pragma unroll
      for (int r = 0; r < 16; ++r) {
        int m = mb + (r & 3) + 8 * (r >> 2);
        int b = m >> d;
        int id = m & (n - 1);
        float gi = sigmoid_f(acc[f][0][r] + b0);
        float go = sigmoid_f(acc[f][3][r] + b3);
        float gu = tanh_f(acc[f][4][r] + b4);
        float cv = gi * gu;
        if (!LEAF) {
          float gl = sigmoid_f(acc[f][1][r] + b1);
          float gr = sigmoid_f(acc[f][2][r] + b2);
          size_t cb = ((size_t)b * 2 * n + 2 * id) * HDIM + j;
          cv += gl * c_prev[cb] + gr * c_prev[cb + HDIM];
        }
        size_t ob = ((size_t)b * n + id) * HDIM + j;
        c_out[ob] = cv;
        h_out[ob] = (__bf16)(go * tanh_f(cv));
      }
    }
  }
}

__global__ __launch_bounds__(256, 2) void fused_kernel(
    const float* __restrict__ x,
    const float* __restrict__ W0, const float* __restrict__ W1,
    const float* __restrict__ W2, const float* __restrict__ W3,
    const float* __restrict__ W4,
    const float* __restrict__ bv0, const float* __restrict__ bv1,
    const float* __restrict__ bv2, const float* __restrict__ bv3,
    const float* __restrict__ bv4,
    const float* __restrict__ Wcls, const float* __restrict__ bcls,
    __bf16* hb0, __bf16* hb1, float* cb0, float* cb1,
    __bf16* PW, float* out)
{
  __shared__ unsigned char Ab[2 * 32768];   // A tile double buffer (64 KB)

  const unsigned base = g_base;             // epoch (stable this launch)
  const int tid = threadIdx.x;
  const int jt = (blockIdx.x >> 3) & 3;
  const int stripe = (int)(blockIdx.x & 7) | ((int)(blockIdx.x >> 5) << 3);

  // ---- phase 0: pack weights into bf16 fragment order (grid-wide) ----
  {
    int gt = blockIdx.x * 256 + tid;
    if (gt < 5 * 4 * 24 * 64) {
      int lane = gt & 63;
      int rest = gt >> 6;
      int ks = rest % 24;
      int r2 = rest / 24;
      int jjt = r2 & 3;
      int g = r2 >> 2;
      const float* W = (g == 0) ? W0 : (g == 1) ? W1 : (g == 2) ? W2 : (g == 3) ? W3 : W4;
      const float* s = W + (size_t)(jjt * 32 + (lane & 31)) * GDIM + ks * 16 + (lane >> 5) * 8;
      float4 v0 = *(const float4*)s;
      float4 v1 = *(const float4*)(s + 4);
      bf16x8 wv;
      wv[0] = (__bf16)v0.x; wv[1] = (__bf16)v0.y; wv[2] = (__bf16)v0.z; wv[3] = (__bf16)v0.w;
      wv[4] = (__bf16)v1.x; wv[5] = (__bf16)v1.y; wv[6] = (__bf16)v1.z; wv[7] = (__bf16)v1.w;
      *(bf16x8*)(PW + (size_t)gt * 8) = wv;
    }
  }
  gbar(base, 1);

  const int l = tid & 63;
  const int j = jt * 32 + (l & 31);
  const float b0 = bv0[j], b1 = bv1[j], b2 = bv2[j], b3 = bv3[j], b4 = bv4[j];

  // ---- leaf level d=9 (K=128, fl/fr skipped) -> hb0/cb0 ----
  level_body<true>(Ab, x, PW, hb1, cb1, hb0, cb0, 9, jt, stripe, b0, b1, b2, b3, b4, j);
  gbar(base, 2);

  // ---- levels d=8..0 ----
  unsigned k = 3;
  for (int d = 8; d >= 0; --d, ++k) {
    const int p = 9 - d;
    __bf16* h_out = (p & 1) ? hb1 : hb0;
    float*  c_out = (p & 1) ? cb1 : cb0;
    const __bf16* h_prev = (p & 1) ? hb0 : hb1;
    const float*  c_prev = (p & 1) ? cb0 : cb1;
    level_body<false>(Ab, x, PW, h_prev, c_prev, h_out, c_out, d, jt, stripe,
                      b0, b1, b2, b3, b4, j);
    gbar(base, k);
  }

  // ---- classifier (root h in hb1) + epoch update ----
  if (blockIdx.x == 0) {
    if (tid < BATCH) {
      const __bf16* hr = hb1 + (size_t)tid * HDIM;
      float s[NCLS];
#pragma unroll
      for (int c = 0; c < NCLS; ++c) s[c] = bcls[c];
      for (int kk = 0; kk < HDIM; ++kk) {
        float hv = (float)hr[kk];
#pragma unroll
        for (int c = 0; c < NCLS; ++c) s[c] += hv * Wcls[c * HDIM + kk];
      }
#pragma unroll
      for (int c = 0; c < NCLS; ++c) out[tid * NCLS + c] = s[c];
    }
    if (tid == 0)
      __hip_atomic_store(&g_base, base + (unsigned)NBAR * (unsigned)NBLK,
                         __ATOMIC_RELAXED, __HIP_MEMORY_SCOPE_AGENT);
  }
}

extern "C" void kernel_launch(void* const* d_in, const int* in_sizes, int n_in,
                              void* d_out, int out_size, void* d_ws, size_t ws_size,
                              hipStream_t stream) {
  const float* x  = (const float*)d_in[0];
  const float* W[5]  = {(const float*)d_in[1], (const float*)d_in[3], (const float*)d_in[5],
                        (const float*)d_in[7], (const float*)d_in[9]};
  const float* bv[5] = {(const float*)d_in[2], (const float*)d_in[4], (const float*)d_in[6],
                        (const float*)d_in[8], (const float*)d_in[10]};
  const float* Wcls = (const float*)d_in[11];
  const float* bcls = (const float*)d_in[12];

  uint8_t* ws = (uint8_t*)d_ws;
  __bf16* hb0 = (__bf16*)ws;                       // 32 MiB (levels 9,7,5,3,1)
  __bf16* hb1 = (__bf16*)(ws + 33554432);          // 16 MiB (levels 8,6,4,2,0)
  float*  cb0 = (float*)(ws + 50331648);           // 64 MiB
  float*  cb1 = (float*)(ws + 117440512);          // 32 MiB
  __bf16* PW  = (__bf16*)(ws + 150994944);         // 480 KB packed weights

  fused_kernel<<<NBLK, 256, 0, stream>>>(
      x, W[0], W[1], W[2], W[3], W[4],
      bv[0], bv[1], bv[2], bv[3], bv[4],
      Wcls, bcls, hb0, hb1, cb0, cb1, PW, (float*)d_out);
}

// Round 7
// 541.488 us; speedup vs baseline: 3.5465x; 3.5465x over previous
//
#include <hip/hip_runtime.h>
#include <hip/hip_bf16.h>
#include <stdint.h>

// BinaryTreeLSTM on MI355X (gfx950) — round 7.
// R2-proven structure (16x16x32 MFMA, acc=80 floats/wave, coalesced LDS
// staging, per-level launches for heavy levels) with the measured limiters
// removed:
//  - All LDS traffic in 1KB lane-linear fragment chunks: frag reads are
//    ds_read_b128 at base+lane*16 (conflict-free); staging via
//    global_load_lds (B from frag-packed PW, A h-region) or in-register
//    fp32->bf16 cvt + lane-linear ds_write_b128 (A x-region).
//  - Zero per-level weight conversion (pack_w once -> PW, 480KB).
//  - d=9..6 as 4 launches; d=5..0 + classifier in ONE persistent 128-block
//    tail kernel with device-scope grid barriers (kills small-launch tail).
//  - acc[2][2][5] f32x4 = 80 floats/wave -> no spills (R5/R6 lesson).

#define BATCH 256
#define NTOT 1023
#define HDIM 128
#define NCLS 5
#define GDIM 384
#define NBLKC 128   // tail kernel grid

typedef __bf16 bf16x8 __attribute__((ext_vector_type(8)));
typedef float f32x4 __attribute__((ext_vector_type(4)));

__device__ unsigned g_ctr;    // zero-init at module load; monotonic forever
__device__ unsigned g_base;   // epoch base for current launch

__device__ __forceinline__ float sigmoid_f(float v) { return 1.f / (1.f + __expf(-v)); }
__device__ __forceinline__ float tanh_f(float v) { return 1.f - 2.f / (1.f + __expf(2.f * v)); }

__device__ __forceinline__ void load_lds16(const void* g, void* l) {
  __builtin_amdgcn_global_load_lds((const __attribute__((address_space(1))) unsigned int*)g,
                                   (__attribute__((address_space(3))) unsigned int*)l, 16, 0, 0);
}

__device__ __forceinline__ void gbar(unsigned base, unsigned k) {
  __syncthreads();
  if (threadIdx.x == 0) {
    __threadfence();
    __hip_atomic_fetch_add(&g_ctr, 1u, __ATOMIC_RELAXED, __HIP_MEMORY_SCOPE_AGENT);
    while ((unsigned)(__hip_atomic_load(&g_ctr, __ATOMIC_RELAXED, __HIP_MEMORY_SCOPE_AGENT) - base)
           < k * (unsigned)NBLKC)
      __builtin_amdgcn_s_sleep(1);
    (void)__hip_atomic_load(&g_ctr, __ATOMIC_ACQUIRE, __HIP_MEMORY_SCOPE_AGENT);
  }
  __syncthreads();
}

// PW: 480 chunks of 1KB. chunk = (g*8 + jf)*12 + ks; lane l holds
// W[g][jf*16 + (l&15)][ks*32 + (l>>4)*8 + i], i=0..7  (16x16x32 b-frag order)
__global__ __launch_bounds__(256) void pack_w(
    const float* __restrict__ W0, const float* __restrict__ W1, const float* __restrict__ W2,
    const float* __restrict__ W3, const float* __restrict__ W4, __bf16* __restrict__ PW)
{
  int t = blockIdx.x * 256 + threadIdx.x;   // 30720
  int lane = t & 63;
  int chunk = t >> 6;
  int ks = chunk % 12;
  int jf = (chunk / 12) & 7;
  int g = chunk / 96;
  const float* W = (g == 0) ? W0 : (g == 1) ? W1 : (g == 2) ? W2 : (g == 3) ? W3 : W4;
  const float* s = W + (size_t)(jf * 16 + (lane & 15)) * GDIM + ks * 32 + (lane >> 4) * 8;
  float4 v0 = *(const float4*)s;
  float4 v1 = *(const float4*)(s + 4);
  bf16x8 w;
  w[0] = (__bf16)v0.x; w[1] = (__bf16)v0.y; w[2] = (__bf16)v0.z; w[3] = (__bf16)v0.w;
  w[4] = (__bf16)v1.x; w[5] = (__bf16)v1.y; w[6] = (__bf16)v1.z; w[7] = (__bf16)v1.w;
  *(bf16x8*)(PW + (size_t)t * 8) = w;
}

// One 64m x 64j x 5g tile. LDS per buffer: A 4KB (4 chunks) + B 20KB (20 chunks).
template<bool LEAF>
__device__ __forceinline__ void tile_body(
    const float* __restrict__ x, const __bf16* __restrict__ PW,
    const __bf16* __restrict__ h_prev, const float* __restrict__ c_prev,
    __bf16* __restrict__ h_out, float* __restrict__ c_out,
    const float* __restrict__ bv0, const float* __restrict__ bv1,
    const float* __restrict__ bv2, const float* __restrict__ bv3,
    const float* __restrict__ bv4,
    int d, int m0, int j0, unsigned char* lds)
{
  const int tid = threadIdx.x;
  const int w = tid >> 6;
  const int l = tid & 63;
  const int l15 = l & 15;
  const int quad = l >> 4;
  const int q8 = quad * 8;
  const int mh = w & 1, jh = w >> 1;
  const int n = 1 << d;
  const int jfb = j0 >> 4;
  constexpr int NKT = LEAF ? 4 : 12;   // BK=32 k-steps
  constexpr int NBC = LEAF ? 3 : 5;    // B chunks staged per wave per step

  // staging lane's A row: m0 + w*16 + l15 (wave w stages A chunk w)
  const int ms = m0 + w * 16 + l15;
  const int bs = ms >> d;
  const int ids = ms & (n - 1);
  const float* xrow = x + ((size_t)bs * NTOT + (n - 1) + ids) * HDIM;
  const __bf16* hrow = LEAF ? (const __bf16*)nullptr
                            : h_prev + ((size_t)bs * 2 * n + 2 * ids) * HDIM;

  auto stage = [&](int ks) {
    unsigned char* Ab = lds + (ks & 1) * 24576;
    unsigned char* Bb = Ab + 4096;
#pragma unroll
    for (int q = 0; q < NBC; ++q) {
      int c = w * NBC + q;
      int g;
      if (LEAF) { const int gm[3] = {0, 3, 4}; g = gm[c >> 2]; }
      else g = c >> 2;
      int jfl = c & 3;
      const __bf16* s = PW + (((size_t)(g * 8 + jfb + jfl) * 12 + ks) * 64 + l) * 8;
      load_lds16(s, Bb + (g * 4 + jfl) * 1024);
    }
    if (LEAF || ks < 4) {
      const float* s = xrow + ks * 32 + q8;
      float4 v0 = *(const float4*)s;
      float4 v1 = *(const float4*)(s + 4);
      bf16x8 wv;
      wv[0] = (__bf16)v0.x; wv[1] = (__bf16)v0.y; wv[2] = (__bf16)v0.z; wv[3] = (__bf16)v0.w;
      wv[4] = (__bf16)v1.x; wv[5] = (__bf16)v1.y; wv[6] = (__bf16)v1.z; wv[7] = (__bf16)v1.w;
      *(bf16x8*)(Ab + w * 1024 + l * 16) = wv;
    } else {
      int off = (ks < 8) ? (ks - 4) * 32 : 128 + (ks - 8) * 32;
      load_lds16(hrow + off + q8, Ab + w * 1024);
    }
  };

  f32x4 acc[2][2][5];
#pragma unroll
  for (int mf = 0; mf < 2; ++mf)
#pragma unroll
    for (int jfl = 0; jfl < 2; ++jfl)
#pragma unroll
      for (int g = 0; g < 5; ++g)
        acc[mf][jfl][g] = (f32x4){0.f, 0.f, 0.f, 0.f};

  stage(0);
  for (int ks = 0; ks < NKT; ++ks) {
    __syncthreads();                     // buf ks&1 staged; other buf free
    if (ks + 1 < NKT) stage(ks + 1);
    const unsigned char* Ab = lds + (ks & 1) * 24576;
    const unsigned char* Bb = Ab + 4096;
    bf16x8 a0 = *(const bf16x8*)(Ab + (mh * 2 + 0) * 1024 + l * 16);
    bf16x8 a1 = *(const bf16x8*)(Ab + (mh * 2 + 1) * 1024 + l * 16);
#pragma unroll
    for (int g = 0; g < 5; ++g) {
      if (LEAF && (g == 1 || g == 2)) continue;   // children zero -> fl/fr unused
#pragma unroll
      for (int jfl = 0; jfl < 2; ++jfl) {
        bf16x8 bb = *(const bf16x8*)(Bb + (g * 4 + jh * 2 + jfl) * 1024 + l * 16);
        acc[0][jfl][g] = __builtin_amdgcn_mfma_f32_16x16x32_bf16(a0, bb, acc[0][jfl][g], 0, 0, 0);
        acc[1][jfl][g] = __builtin_amdgcn_mfma_f32_16x16x32_bf16(a1, bb, acc[1][jfl][g], 0, 0, 0);
      }
    }
  }

  // epilogue: D layout col(j)=lane&15, row(m)=quad*4+r  (verified R1)
#pragma unroll
  for (int jfl = 0; jfl < 2; ++jfl) {
    const int je = j0 + jh * 32 + jfl * 16 + l15;
    const float b0 = bv0[je], b1 = bv1[je], b2 = bv2[je], b3 = bv3[je], b4 = bv4[je];
#pragma unroll
    for (int mf = 0; mf < 2; ++mf) {
#pragma unroll
      for (int r = 0; r < 4; ++r) {
        int me = m0 + mh * 32 + mf * 16 + quad * 4 + r;
        int b = me >> d;
        int id = me & (n - 1);
        float gi = sigmoid_f(acc[mf][jfl][0][r] + b0);
        float go = sigmoid_f(acc[mf][jfl][3][r] + b3);
        float gu = tanh_f(acc[mf][jfl][4][r] + b4);
        float cv = gi * gu;
        if (!LEAF) {
          float gl = sigmoid_f(acc[mf][jfl][1][r] + b1);
          float gr = sigmoid_f(acc[mf][jfl][2][r] + b2);
          size_t cbase = ((size_t)b * 2 * n + 2 * id) * HDIM + je;
          cv += gl * c_prev[cbase] + gr * c_prev[cbase + HDIM];
        }
        size_t ob = ((size_t)b * n + id) * HDIM + je;
        c_out[ob] = cv;
        h_out[ob] = (__bf16)(go * tanh_f(cv));
      }
    }
  }
}

template<bool LEAF>
__global__ __launch_bounds__(256, 2) void level_kernel(
    const float* __restrict__ x, const __bf16* __restrict__ PW,
    const float* __restrict__ bv0, const float* __restrict__ bv1,
    const float* __restrict__ bv2, const float* __restrict__ bv3,
    const float* __restrict__ bv4,
    const __bf16* __restrict__ h_prev, const float* __restrict__ c_prev,
    __bf16* __restrict__ h_out, float* __restrict__ c_out, int d)
{
  __shared__ unsigned char lds[49152];
  tile_body<LEAF>(x, PW, h_prev, c_prev, h_out, c_out,
                  bv0, bv1, bv2, bv3, bv4, d,
                  (int)blockIdx.x * 64, (int)blockIdx.y * 64, lds);
}

__global__ __launch_bounds__(256, 2) void tail_kernel(
    const float* __restrict__ x, const __bf16* __restrict__ PW,
    const float* __restrict__ bv0, const float* __restrict__ bv1,
    const float* __restrict__ bv2, const float* __restrict__ bv3,
    const float* __restrict__ bv4,
    const float* __restrict__ Wcls, const float* __restrict__ bcls,
    __bf16* hb0, __bf16* hb1, float* cb0, float* cb1, float* out)
{
  __shared__ unsigned char lds[49152];
  const unsigned base = g_base;
  unsigned k = 1;
  for (int d = 5; d >= 0; --d, ++k) {
    const int p = 9 - d;
    __bf16* h_out = (p & 1) ? hb1 : hb0;
    float*  c_out = (p & 1) ? cb1 : cb0;
    const __bf16* h_prev = (p & 1) ? hb0 : hb1;
    const float*  c_prev = (p & 1) ? cb0 : cb1;
    const int units = ((BATCH << d) >> 6) * 2;   // (M/64) * 2 j-halves
    for (int u = blockIdx.x; u < units; u += NBLKC) {
      tile_body<false>(x, PW, h_prev, c_prev, h_out, c_out,
                       bv0, bv1, bv2, bv3, bv4, d,
                       (u >> 1) * 64, (u & 1) * 64, lds);
    }
    gbar(base, k);
  }
  // classifier: root h in hb1 (p=9)
  if (blockIdx.x == 0) {
    if (threadIdx.x < BATCH) {
      const __bf16* hr = hb1 + (size_t)threadIdx.x * HDIM;
      float s[NCLS];
#pragma unroll
      for (int c = 0; c < NCLS; ++c) s[c] = bcls[c];
      for (int kk = 0; kk < HDIM; ++kk) {
        float hv = (float)hr[kk];
#pragma unroll
        for (int c = 0; c < NCLS; ++c) s[c] += hv * Wcls[c * HDIM + kk];
      }
#pragma unroll
      for (int c = 0; c < NCLS; ++c) out[threadIdx.x * NCLS + c] = s[c];
    }
    if (threadIdx.x == 0)
      __hip_atomic_store(&g_base, base + 6u * (unsigned)NBLKC,
                         __ATOMIC_RELAXED, __HIP_MEMORY_SCOPE_AGENT);
  }
}

extern "C" void kernel_launch(void* const* d_in, const int* in_sizes, int n_in,
                              void* d_out, int out_size, void* d_ws, size_t ws_size,
                              hipStream_t stream) {
  const float* x  = (const float*)d_in[0];
  const float* W[5]  = {(const float*)d_in[1], (const float*)d_in[3], (const float*)d_in[5],
                        (const float*)d_in[7], (const float*)d_in[9]};
  const float* bv[5] = {(const float*)d_in[2], (const float*)d_in[4], (const float*)d_in[6],
                        (const float*)d_in[8], (const float*)d_in[10]};
  const float* Wcls = (const float*)d_in[11];
  const float* bcls = (const float*)d_in[12];

  uint8_t* ws = (uint8_t*)d_ws;
  __bf16* hb0 = (__bf16*)ws;                       // 32 MiB (d = 9,7,5,3,1)
  __bf16* hb1 = (__bf16*)(ws + 33554432);          // 16 MiB (d = 8,6,4,2,0)
  float*  cb0 = (float*)(ws + 50331648);           // 64 MiB
  float*  cb1 = (float*)(ws + 117440512);          // 32 MiB
  __bf16* PW  = (__bf16*)(ws + 150994944);         // 480 KB frag-packed weights

  pack_w<<<120, 256, 0, stream>>>(W[0], W[1], W[2], W[3], W[4], PW);

  // leaf d=9 -> hb0/cb0
  level_kernel<true><<<dim3(2048, 2), 256, 0, stream>>>(
      x, PW, bv[0], bv[1], bv[2], bv[3], bv[4], hb1, cb1, hb0, cb0, 9);
  // d=8..6
  for (int d = 8; d >= 6; --d) {
    const int p = 9 - d;
    __bf16* h_out = (p & 1) ? hb1 : hb0;
    float*  c_out = (p & 1) ? cb1 : cb0;
    const __bf16* h_prev = (p & 1) ? hb0 : hb1;
    const float*  c_prev = (p & 1) ? cb0 : cb1;
    dim3 grid((BATCH << d) >> 6, 2);
    level_kernel<false><<<grid, 256, 0, stream>>>(
        x, PW, bv[0], bv[1], bv[2], bv[3], bv[4], h_prev, c_prev, h_out, c_out, d);
  }
  // d=5..0 + classifier, persistent with grid barriers
  tail_kernel<<<NBLKC, 256, 0, stream>>>(
      x, PW, bv[0], bv[1], bv[2], bv[3], bv[4],
      Wcls, bcls, hb0, hb1, cb0, cb1, (float*)d_out);
}